// Round 10
// baseline (599.338 us; speedup 1.0000x reference)
//
#include <hip/hip_runtime.h>
#include <hip/hip_bf16.h>

constexpr int BB = 4, HH = 64, WW = 64, DMv = 96;
constexpr int DSn = 16, DIv = 192, DTRv = 6, KKv = 4, HIDv = 768;
constexpr int LL = 4096;
constexpr int NC = 64, CHK = LL / NC;       // 64 chunks of 64
constexpr int NR = BB * LL;                 // 16384 rows
constexpr int XDS = 40;                     // padded xdbl row stride (dt 0-5, B 8-23, C 24-39)

constexpr size_t S_xi   = (size_t)BB * LL * DIv;          // 3,145,728
constexpr size_t S_xdbl = (size_t)BB * KKv * LL * XDS;    // 2,621,440
constexpr size_t S_big  = (size_t)BB * KKv * LL * DIv;    // 12,582,912
constexpr size_t S_sp   = (size_t)BB * KKv * NC * DIv * DSn;  // 3,145,728 at NC=64

typedef __attribute__((ext_vector_type(8))) short short8;   // 8 bf16 (4 VGPRs)
typedef __attribute__((ext_vector_type(4))) short short4v;  // 4 bf16
typedef __attribute__((ext_vector_type(4))) float floatx4;  // MFMA accumulator

__device__ __forceinline__ float sigf(float x) { return 1.f / (1.f + __expf(-x)); }
__device__ __forceinline__ float softp(float x) {
  return (x > 20.f) ? x : __logf(1.f + __expf(x));
}
__device__ __forceinline__ short bfbits(float v) {
  __hip_bfloat16 h = __float2bfloat16(v);
  return *(short*)&h;
}

__device__ __forceinline__ int lmap(int k, int l) {
  int lr = (k & 2) ? (LL - 1 - l) : l;
  return (k & 1) ? (((lr & 63) << 6) | (lr >> 6)) : lr;
}

// K0: merged weight prep + x bf16 hi/lo convert + fragment packing.
// 0..383 xBh/xBl | 384..419 inwP(hi/lo) | 420..491 fiwP | 492..509 opwP(hi/lo) |
// 510..581 fowP(hi/lo) | 582..611 wcatP(hi/lo).
__global__ void k_wprep(const float* __restrict__ fiw, const float* __restrict__ opw,
                        const float* __restrict__ fow, const float* __restrict__ in_w,
                        const float* __restrict__ xpw, const float* __restrict__ x,
                        short* __restrict__ xBh, short* __restrict__ xBl,
                        short* __restrict__ inwP, short* __restrict__ fiwP,
                        short* __restrict__ opwP, short* __restrict__ fowP,
                        short* __restrict__ wcatP) {
  int bx = blockIdx.x, t = threadIdx.x;
  if (bx < 384) {  // x -> bf16 hi/lo, row-major streaming (NR*96 = 1.57M elems)
    const float4* x4 = (const float4*)x;
#pragma unroll
    for (int i = 0; i < 4; ++i) {
      int idx4 = bx * 1024 + i * 256 + t;     // < 393216
      float4 v = x4[idx4];
      short4v hh, ll;
#pragma unroll
      for (int j = 0; j < 4; ++j) {
        float val = (&v.x)[j];
        __hip_bfloat16 h = __float2bfloat16(val);
        hh[j] = *(short*)&h;
        ll[j] = bfbits(val - (float)h);
      }
      *(short4v*)(xBh + (size_t)idx4 * 4) = hh;
      *(short4v*)(xBl + (size_t)idx4 * 4) = ll;
    }
    return;
  }
  int lane = t & 63, ln16 = lane & 15, qd = lane >> 4;
  if (bx < 420) {  // inwP hi/lo: in_w [384][96]; frag f = kt*24+ntg (kt<3)
    int u = (bx - 384) * 4 + (t >> 6);   // 0..143
    int f = u >> 1, part = u & 1;        // f 0..71
    int kt = f / 24, ntg = f % 24;
    int n = ntg * 16 + ln16;
#pragma unroll
    for (int j = 0; j < 8; ++j) {
      int k = kt * 32 + qd * 8 + j;
      float w = in_w[(size_t)n * 96 + k];
      __hip_bfloat16 h = __float2bfloat16(w);
      float v = part ? (w - (float)h) : w;
      inwP[((size_t)(part * 72 + f)) * 512 + lane * 8 + j] = bfbits(v);
    }
    return;
  }
  if (bx < 492) {  // fiwP (hi only): frag f = kt*48+ntg
    int f = (bx - 420) * 4 + (t >> 6);   // 0..287
    int kt = f / 48, ntg = f % 48;
    int n = ntg * 16 + ln16;
#pragma unroll
    for (int j = 0; j < 8; ++j) {
      int k = kt * 32 + qd * 8 + j;
      fiwP[(size_t)f * 512 + lane * 8 + j] = bfbits(fiw[(size_t)n * DIv + k]);
    }
    return;
  }
  if (bx < 510) {  // opwP hi/lo: opw [96][192]; frag f = kt*6+ntg (kt<6)
    int u = (bx - 492) * 4 + (t >> 6);   // 0..71
    int f = u >> 1, part = u & 1;
    int kt = f / 6, ntg = f % 6;
    int n = ntg * 16 + ln16;
#pragma unroll
    for (int j = 0; j < 8; ++j) {
      int k = kt * 32 + qd * 8 + j;
      float w = opw[(size_t)n * DIv + k];
      __hip_bfloat16 h = __float2bfloat16(w);
      float v = part ? (w - (float)h) : w;
      opwP[((size_t)(part * 36 + f)) * 512 + lane * 8 + j] = bfbits(v);
    }
    return;
  }
  if (bx < 582) {  // fowP hi/lo: fow [96][768]; frag f = kt*6+ntg (kt<24)
    int u = (bx - 510) * 4 + (t >> 6);  // 0..287
    int f = u >> 1, part = u & 1;
    int kt = f / 6, ntg = f % 6;
    int n = ntg * 16 + ln16;
#pragma unroll
    for (int j = 0; j < 8; ++j) {
      int k = kt * 32 + qd * 8 + j;
      float w = fow[(size_t)n * HIDv + k];
      __hip_bfloat16 h = __float2bfloat16(w);
      float v = part ? (w - (float)h) : w;
      fowP[((size_t)(part * 144 + f)) * 512 + lane * 8 + j] = bfbits(v);
    }
    return;
  }
  {  // wcatP hi/lo: x_proj weights as B-frags; u -> p/part/kt/g
    int u = (bx - 582) * 4 + (t >> 6);  // 0..119
    int p = u / 60, r = u % 60;
    int part = r / 30, r2 = r % 30;
    int kt = r2 / 5, g = r2 % 5;
    int n = g * 16 + ln16;              // output col 0..79 (76..79 pad)
#pragma unroll
    for (int j = 0; j < 8; ++j) {
      int kd = kt * 32 + qd * 8 + j;
      float w = 0.f;
      if (n < 76) {
        int ksel = ((n >= 38) ? 2 : 0) + p;
        int cc = (n >= 38) ? n - 38 : n;
        w = xpw[(size_t)(ksel * 38 + cc) * DIv + kd];
      }
      __hip_bfloat16 h = __float2bfloat16(w);
      float v = part ? (w - (float)h) : w;
      wcatP[((size_t)(((p * 2 + part) * 6 + kt) * 5 + g)) * 512 + lane * 8 + j] = bfbits(v);
    }
  }
}

// K1 (MFMA): xz = x @ in_proj_w.T via 3-term hi/lo bf16. Grid (NR/64, 6).
__global__ void k_inprojmf(const short* __restrict__ xBh, const short* __restrict__ xBl,
                           const short* __restrict__ inwP,
                           float* __restrict__ xi, float* __restrict__ z) {
  int t = threadIdx.x;            // 256
  int wv = t >> 6, lane = t & 63;
  int ln16 = lane & 15, qd = lane >> 4;
  int m0 = blockIdx.x * 64 + wv * 16;
  int ntg0 = blockIdx.y * 4;      // 4 of 24 col-groups
  floatx4 acc[4];
  floatx4 zero4 = {0.f, 0.f, 0.f, 0.f};
#pragma unroll
  for (int nt = 0; nt < 4; ++nt) acc[nt] = zero4;
  const short* arh = xBh + (size_t)(m0 + ln16) * 96 + qd * 8;
  const short* arl = xBl + (size_t)(m0 + ln16) * 96 + qd * 8;
#pragma unroll
  for (int kt = 0; kt < 3; ++kt) {
    short8 ah = *(const short8*)(arh + kt * 32);
    short8 al = *(const short8*)(arl + kt * 32);
    const short* bh = inwP + ((size_t)(kt * 24 + ntg0) * 64 + lane) * 8;
    const short* bl = inwP + ((size_t)(72 + kt * 24 + ntg0) * 64 + lane) * 8;
#pragma unroll
    for (int nt = 0; nt < 4; ++nt) {
      short8 Bh = *(const short8*)(bh + (size_t)nt * 512);
      short8 Bl = *(const short8*)(bl + (size_t)nt * 512);
      acc[nt] = __builtin_amdgcn_mfma_f32_16x16x32_bf16(ah, Bh, acc[nt], 0, 0, 0);
      acc[nt] = __builtin_amdgcn_mfma_f32_16x16x32_bf16(al, Bh, acc[nt], 0, 0, 0);
      acc[nt] = __builtin_amdgcn_mfma_f32_16x16x32_bf16(ah, Bl, acc[nt], 0, 0, 0);
    }
  }
#pragma unroll
  for (int nt = 0; nt < 4; ++nt) {
    int col = blockIdx.y * 64 + nt * 16 + ln16;   // 0..383; uniform xi/z per block
#pragma unroll
    for (int r = 0; r < 4; ++r) {
      int row = m0 + qd * 4 + r;
      float v = acc[nt][r];
      if (col < DIv) xi[(size_t)row * DIv + col] = v;
      else           z[(size_t)row * DIv + col - DIv] = v;
    }
  }
}

// K2: xc = silu(dwconv3x3(xi)+b); emits xc f32 + bf16 hi/lo row-major.
constexpr int TW2 = 18;
__global__ void k_dwconv3(const float* __restrict__ xi, const float* __restrict__ cw,
                          const float* __restrict__ cb, float* __restrict__ xc,
                          short* __restrict__ xcBh, short* __restrict__ xcBl) {
  int tile = blockIdx.x;
  int cg = blockIdx.y, b = blockIdx.z;
  int t = threadIdx.x;
  int ti0 = (tile >> 2) * 16, tj0 = (tile & 3) * 16;
  __shared__ float sm[TW2 * TW2 * 32];

  for (int e = t; e < TW2 * TW2 * 32; e += 256) {
    int ec = e & 31;
    int sp = e >> 5;
    int hi = sp / TW2, hj = sp % TW2;
    int gi = ti0 + hi - 1, gj = tj0 + hj - 1;
    float v = 0.f;
    if ((unsigned)gi < (unsigned)HH && (unsigned)gj < (unsigned)WW)
      v = xi[((size_t)b * LL + gi * WW + gj) * DIv + cg * 32 + ec];
    sm[e] = v;
  }

  int c = t & 31, s0 = t >> 5;
  int cglob = cg * 32 + c;
  float wc[9];
#pragma unroll
  for (int j = 0; j < 9; ++j) wc[j] = cw[cglob * 9 + j];
  float bv = cb[cglob];
  __syncthreads();

  float res[32];
  for (int i = 0; i < 32; ++i) {
    int p = s0 + (i << 3);
    int r = p >> 4, q = p & 15;
    float s = bv;
#pragma unroll
    for (int di = 0; di < 3; ++di)
#pragma unroll
      for (int dj = 0; dj < 3; ++dj)
        s += sm[((r + di) * TW2 + (q + dj)) * 32 + c] * wc[di * 3 + dj];
    res[i] = s * sigf(s);
  }
  __syncthreads();
  for (int i = 0; i < 32; ++i) {
    int p = s0 + (i << 3);
    sm[p * 35 + c] = res[i];
  }
  __syncthreads();
  for (int it = 0; it < 32; ++it) {
    int e = it * 256 + t;
    int p = e >> 5, ec = e & 31;
    int l = (ti0 + (p >> 4)) * WW + tj0 + (p & 15);
    float v = sm[p * 35 + ec];
    size_t idx = ((size_t)b * LL + l) * DIv + cg * 32 + ec;
    xc[idx] = v;
    __hip_bfloat16 hh = __float2bfloat16(v);
    xcBh[idx] = *(short*)&hh;
    xcBl[idx] = bfbits(v - (float)hh);
  }
}

// K3 (MFMA): x_dbl = xs @ x_proj_w via hi/lo bf16; transpose folded into A rows.
__global__ void k_xdblmf(const short* __restrict__ xcBh, const short* __restrict__ xcBl,
                         const short* __restrict__ wcatP, float* __restrict__ xdbl) {
  int t = threadIdx.x;            // 256
  int wv = t >> 6, lane = t & 63;
  int ln16 = lane & 15, qd = lane >> 4;
  int pb = blockIdx.y;
  int p = pb >> 2, b = pb & 3;
  int m0 = blockIdx.x * 64 + wv * 16;
  int r = m0 + ln16;
  int l = p ? (((r & 63) << 6) | (r >> 6)) : r;
  const short* ah = xcBh + ((size_t)(b * LL + l)) * DIv + qd * 8;
  const short* al = xcBl + ((size_t)(b * LL + l)) * DIv + qd * 8;
  floatx4 acc[5];
  floatx4 zero4 = {0.f, 0.f, 0.f, 0.f};
#pragma unroll
  for (int g = 0; g < 5; ++g) acc[g] = zero4;
#pragma unroll
  for (int kt = 0; kt < 6; ++kt) {
    short8 Ah = *(const short8*)(ah + kt * 32);
    short8 Al = *(const short8*)(al + kt * 32);
    const short* bh = wcatP + ((size_t)(((p * 2 + 0) * 6 + kt) * 5)) * 512 + lane * 8;
    const short* bl = wcatP + ((size_t)(((p * 2 + 1) * 6 + kt) * 5)) * 512 + lane * 8;
#pragma unroll
    for (int g = 0; g < 5; ++g) {
      short8 Bh = *(const short8*)(bh + (size_t)g * 512);
      short8 Bl = *(const short8*)(bl + (size_t)g * 512);
      acc[g] = __builtin_amdgcn_mfma_f32_16x16x32_bf16(Ah, Bh, acc[g], 0, 0, 0);
      acc[g] = __builtin_amdgcn_mfma_f32_16x16x32_bf16(Al, Bh, acc[g], 0, 0, 0);
      acc[g] = __builtin_amdgcn_mfma_f32_16x16x32_bf16(Ah, Bl, acc[g], 0, 0, 0);
    }
  }
#pragma unroll
  for (int g = 0; g < 5; ++g) {
    int col = g * 16 + ln16;
    if (col < 76) {
#pragma unroll
      for (int rr = 0; rr < 4; ++rr) {
        int rowr = m0 + qd * 4 + rr;
        int kk = (col >= 38) ? (2 + p) : p;
        int cc = (col >= 38) ? col - 38 : col;
        int lpos = (col >= 38) ? (LL - 1 - rowr) : rowr;
        int phys = cc + (cc >= 6 ? 2 : 0);
        size_t ro = (((size_t)(b * KKv + kk)) * LL + lpos) * XDS;
        xdbl[ro + phys] = acc[g][rr];
        if (col == 5) { xdbl[ro + 6] = 0.f; xdbl[ro + 7] = 0.f; }
      }
    }
  }
}

// K4a: chunked scan pass 1. 32-row tiles (2 barriers/tile = 4/chunk); de from
// global dt cols. INNER MATH FROZEN (R6 form: 4x __expf, A[4]) — R5/R7 exp
// restructures caused scratch-spill codegen. Staging geometry only differs.
__global__ void k_scan1(const float* __restrict__ xdbl, const float* __restrict__ xc,
                        const float* __restrict__ alogs, const float* __restrict__ dtw,
                        const float* __restrict__ dtb,
                        float* __restrict__ S, float* __restrict__ P) {
  int bx = blockIdx.x;
  int c = bx / 3, dblk = bx % 3;
  int k = blockIdx.y, b = blockIdx.z;
  int t = threadIdx.x, dl = t >> 2, nq = t & 3;
  int d = dblk * 64 + dl;
  __shared__ float de_s[32][64], xv_s[32][64], bc_s[32][16];
  float A[4];
#pragma unroll
  for (int j = 0; j < 4; ++j)
    A[j] = -__expf(alogs[(size_t)(k * DIv + d) * DSn + nq * 4 + j]);
  int derow = t >> 4, dec0 = (t & 15) * 4;
  float DTW[4][6], DTB[4];
#pragma unroll
  for (int jj = 0; jj < 4; ++jj) {
    int dd = k * DIv + dblk * 64 + dec0 + jj;
    DTB[jj] = dtb[dd];
#pragma unroll
    for (int r2 = 0; r2 < 6; ++r2) DTW[jj][r2] = dtw[(size_t)dd * 6 + r2];
  }
  size_t bkL = (size_t)(b * KKv + k) * LL;
  const float* xq = xdbl + bkL * XDS;
  const float* xcb = xc + (size_t)b * LL * DIv;
  float h[4] = {0.f, 0.f, 0.f, 0.f}, sA[4] = {0.f, 0.f, 0.f, 0.f};
  int l0 = c * CHK;
  for (int tile = 0; tile < CHK / 32; ++tile) {
    int lt = l0 + tile * 32;
    __syncthreads();
    {
      int r = t >> 4, q = t & 15;
#pragma unroll
      for (int rr = 0; rr < 2; ++rr) {
        int row = r + rr * 16;
        int lc = lmap(k, lt + row);
        *(float4*)&xv_s[row][q * 4] = *(const float4*)(xcb + (size_t)lc * DIv + dblk * 64 + q * 4);
      }
      if (t < 128) {
        int r2 = t >> 2, q2 = t & 3;
        *(float4*)&bc_s[r2][q2 * 4] = *(const float4*)(xq + (size_t)(lt + r2) * XDS + 8 + q2 * 4);
      }
#pragma unroll
      for (int rr = 0; rr < 2; ++rr) {
        int row = derow + rr * 16;
        const float* dtp = xq + (size_t)(lt + row) * XDS;
        float d0 = dtp[0], d1 = dtp[1], d2 = dtp[2], d3 = dtp[3], d4 = dtp[4], d5 = dtp[5];
#pragma unroll
        for (int jj = 0; jj < 4; ++jj) {
          float s = DTB[jj] + d0 * DTW[jj][0] + d1 * DTW[jj][1] + d2 * DTW[jj][2]
                            + d3 * DTW[jj][3] + d4 * DTW[jj][4] + d5 * DTW[jj][5];
          de_s[row][dec0 + jj] = softp(s);
        }
      }
    }
    __syncthreads();
#pragma unroll
    for (int i2 = 0; i2 < 32; ++i2) {
      float de = de_s[i2][dl];
      float xv = xv_s[i2][dl];
      float4 Bv = *(float4*)&bc_s[i2][nq * 4];
      float db = de * xv;
#pragma unroll
      for (int j = 0; j < 4; ++j) {
        float u = de * A[j];
        sA[j] += u;
        h[j] = h[j] * __expf(u) + db * (&Bv.x)[j];
      }
    }
  }
  size_t o = ((((size_t)(b * KKv + k) * NC + c) * 3 + dblk) * 1024) + (size_t)t * 4;
  float4 hs, ps;
#pragma unroll
  for (int j = 0; j < 4; ++j) { (&hs.x)[j] = h[j]; (&ps.x)[j] = __expf(sA[j]); }
  *(float4*)(S + o) = hs;
  *(float4*)(P + o) = ps;
}

// K4b: sequential chunk combine (float4 per thread). Rewrites S[c] <- Hin[c].
__global__ void k_scan2(float* __restrict__ S, const float* __restrict__ P) {
  int dblk = blockIdx.x, k = blockIdx.y, b = blockIdx.z;
  int t = threadIdx.x;
  size_t base = (((size_t)(b * KKv + k) * NC) * 3 + dblk) * 1024 + (size_t)t * 4;
  float4 h = make_float4(0.f, 0.f, 0.f, 0.f);
  for (int c = 0; c < NC; ++c) {
    size_t o = base + (size_t)c * 3 * 1024;
    float4 s = *(float4*)(S + o), p = *(float4*)(P + o);
    *(float4*)(S + o) = h;
    h.x = s.x + p.x * h.x; h.y = s.y + p.y * h.y;
    h.z = s.z + p.z * h.z; h.w = s.w + p.w * h.w;
  }
}

// K4c: chunked scan pass 3 — 32-row tiles; de from global; y via width-4 shuffle.
// INNER MATH FROZEN (R6 form) — see k_scan1 note.
__global__ void k_scan3(const float* __restrict__ xdbl, const float* __restrict__ xc,
                        const float* __restrict__ alogs, const float* __restrict__ dtw,
                        const float* __restrict__ dtb,
                        const float* __restrict__ Hin, float* __restrict__ ys) {
  int bx = blockIdx.x;
  int c = bx / 3, dblk = bx % 3;
  int k = blockIdx.y, b = blockIdx.z;
  int t = threadIdx.x, dl = t >> 2, nq = t & 3;
  int d = dblk * 64 + dl;
  __shared__ float de_s[32][64], xv_s[32][64], bc_s[32][32];
  float A[4];
#pragma unroll
  for (int j = 0; j < 4; ++j)
    A[j] = -__expf(alogs[(size_t)(k * DIv + d) * DSn + nq * 4 + j]);
  int derow = t >> 4, dec0 = (t & 15) * 4;
  float DTW[4][6], DTB[4];
#pragma unroll
  for (int jj = 0; jj < 4; ++jj) {
    int dd = k * DIv + dblk * 64 + dec0 + jj;
    DTB[jj] = dtb[dd];
#pragma unroll
    for (int r2 = 0; r2 < 6; ++r2) DTW[jj][r2] = dtw[(size_t)dd * 6 + r2];
  }
  size_t bkL = (size_t)(b * KKv + k) * LL;
  const float* xq = xdbl + bkL * XDS;
  const float* xcb = xc + (size_t)b * LL * DIv;
  float* yp = ys + bkL * DIv + d;
  size_t o = ((((size_t)(b * KKv + k) * NC + c) * 3 + dblk) * 1024) + (size_t)t * 4;
  float4 h4 = *(const float4*)(Hin + o);
  float h[4] = {h4.x, h4.y, h4.z, h4.w};
  int l0 = c * CHK;
  for (int tile = 0; tile < CHK / 32; ++tile) {
    int lt = l0 + tile * 32;
    __syncthreads();
    {
      int r = t >> 4, q = t & 15;
#pragma unroll
      for (int rr = 0; rr < 2; ++rr) {
        int row = r + rr * 16;
        int lc = lmap(k, lt + row);
        *(float4*)&xv_s[row][q * 4] = *(const float4*)(xcb + (size_t)lc * DIv + dblk * 64 + q * 4);
      }
      {
        int r2 = t >> 3, q2 = t & 7;
        *(float4*)&bc_s[r2][q2 * 4] = *(const float4*)(xq + (size_t)(lt + r2) * XDS + 8 + q2 * 4);
      }
#pragma unroll
      for (int rr = 0; rr < 2; ++rr) {
        int row = derow + rr * 16;
        const float* dtp = xq + (size_t)(lt + row) * XDS;
        float d0 = dtp[0], d1 = dtp[1], d2 = dtp[2], d3 = dtp[3], d4 = dtp[4], d5 = dtp[5];
#pragma unroll
        for (int jj = 0; jj < 4; ++jj) {
          float s = DTB[jj] + d0 * DTW[jj][0] + d1 * DTW[jj][1] + d2 * DTW[jj][2]
                            + d3 * DTW[jj][3] + d4 * DTW[jj][4] + d5 * DTW[jj][5];
          de_s[row][dec0 + jj] = softp(s);
        }
      }
    }
    __syncthreads();
#pragma unroll
    for (int i2 = 0; i2 < 32; ++i2) {
      float de = de_s[i2][dl];
      float xv = xv_s[i2][dl];
      float4 Bv = *(float4*)&bc_s[i2][nq * 4];
      float4 Cv = *(float4*)&bc_s[i2][16 + nq * 4];
      float db = de * xv;
      float p = 0.f;
#pragma unroll
      for (int j = 0; j < 4; ++j) {
        h[j] = h[j] * __expf(de * A[j]) + db * (&Bv.x)[j];
        p += h[j] * (&Cv.x)[j];
      }
      p += __shfl_down(p, 2, 4);
      p += __shfl_down(p, 1, 4);
      if (nq == 0) yp[(size_t)(lt + i2) * DIv] = p;
    }
  }
}

// K5+K6 fused (8 rows/block for occupancy); emits bf16 hi + lo of gated act.
__global__ void k_comlnt(const float* __restrict__ ys, const float* __restrict__ xc,
                         const float* __restrict__ Ds, const float* __restrict__ z,
                         const float* __restrict__ g, const float* __restrict__ be,
                         __hip_bfloat16* __restrict__ ygtB,
                         __hip_bfloat16* __restrict__ ygtBl) {
  int bl0 = blockIdx.x * 8;
  int b = bl0 >> 12, l0 = bl0 & 4095;
  int t = threadIdx.x;              // 256
  __shared__ float vbuf[8 * 193];
  __shared__ float m_[8], rs_[8];
  {
    int li = t >> 5, lane32 = t & 31;
    size_t base = (size_t)b * KKv * LL * DIv;
    int l = l0 + li;
    int lT = ((l & 63) << 6) | (l >> 6);
    const float* r0 = ys + base + (size_t)l * DIv;
    const float* r2 = ys + base + ((size_t)2 * LL + (LL - 1 - l)) * DIv;
    const float* r1 = ys + base + ((size_t)1 * LL + lT) * DIv;
    const float* r3 = ys + base + ((size_t)3 * LL + (LL - 1 - lT)) * DIv;
    const float* xr = xc + ((size_t)b * LL + l) * DIv;
#pragma unroll
    for (int cc = 0; cc < 6; ++cc) {
      int d = lane32 + cc * 32;
      float sd = Ds[d] + Ds[DIv + d] + Ds[2 * DIv + d] + Ds[3 * DIv + d];
      vbuf[li * 193 + d] = r0[d] + r2[d] + r1[d] + r3[d] + sd * xr[d];
    }
  }
  __syncthreads();
  {
    int r = t >> 5, q = t & 31;
    float s = 0.f, qq = 0.f;
#pragma unroll
    for (int j = 0; j < 6; ++j) {
      float v = vbuf[r * 193 + q + j * 32];
      s += v; qq += v * v;
    }
    s += __shfl_down(s, 16, 32); qq += __shfl_down(qq, 16, 32);
    s += __shfl_down(s, 8, 32);  qq += __shfl_down(qq, 8, 32);
    s += __shfl_down(s, 4, 32);  qq += __shfl_down(qq, 4, 32);
    s += __shfl_down(s, 2, 32);  qq += __shfl_down(qq, 2, 32);
    s += __shfl_down(s, 1, 32);  qq += __shfl_down(qq, 1, 32);
    if (q == 0) {
      float m = s / DIv;
      m_[r] = m;
      rs_[r] = rsqrtf(qq / DIv - m * m + 1e-5f);
    }
  }
  __syncthreads();
  int tc = t & 31, tr = t >> 5;     // tr = row 0..7
#pragma unroll
  for (int ch = 0; ch < 6; ++ch) {
    int c0 = ch * 32;
    float gg = g[c0 + tc], bb = be[c0 + tc];
    float v = vbuf[tr * 193 + c0 + tc];
    float zz = z[(size_t)(bl0 + tr) * DIv + c0 + tc];
    float val = (v - m_[tr]) * rs_[tr] * gg + bb;
    float gated = val * zz * sigf(zz);
    __hip_bfloat16 h = __float2bfloat16(gated);
    ygtB[(size_t)(bl0 + tr) * DIv + c0 + tc] = h;
    ygtBl[(size_t)(bl0 + tr) * DIv + c0 + tc] = __float2bfloat16(gated - (float)h);
  }
}

// K8 (MFMA): hcl = silu(ygated @ ffn_in_w.T + b) in bf16 MFMA, fp32 accumulate.
__global__ void k_ffnmf(const __hip_bfloat16* __restrict__ ygtB,
                        const short* __restrict__ fiwP,
                        const float* __restrict__ bias, float* __restrict__ hcl) {
  int t = threadIdx.x;            // 256
  int wv = t >> 6, lane = t & 63;
  int ln16 = lane & 15, qd = lane >> 4;
  int m0 = blockIdx.x * 64 + wv * 16;
  int n0 = blockIdx.y * 64;
  int ntg0 = n0 >> 4;             // first 16-col group
  floatx4 acc[4];
  floatx4 zero4 = {0.f, 0.f, 0.f, 0.f};
#pragma unroll
  for (int nt = 0; nt < 4; ++nt) acc[nt] = zero4;
  const short* arow = (const short*)ygtB + (size_t)(m0 + ln16) * DIv + qd * 8;
#pragma unroll
  for (int kt = 0; kt < 6; ++kt) {
    short8 a = *(const short8*)(arow + kt * 32);
    const short* bb = fiwP + ((size_t)(kt * 48 + ntg0) * 64 + lane) * 8;
#pragma unroll
    for (int nt = 0; nt < 4; ++nt) {
      short8 bfr = *(const short8*)(bb + (size_t)nt * 512);
      acc[nt] = __builtin_amdgcn_mfma_f32_16x16x32_bf16(a, bfr, acc[nt], 0, 0, 0);
    }
  }
  // C/D layout: col = lane&15, row = (lane>>4)*4 + reg  [m89-verified]
#pragma unroll
  for (int nt = 0; nt < 4; ++nt) {
    int col = n0 + nt * 16 + ln16;
    float bv = bias[col];
#pragma unroll
    for (int r = 0; r < 4; ++r) {
      int row = m0 + qd * 4 + r;
      float s = acc[nt][r] + bv;
      hcl[(size_t)row * HIDv + col] = s * sigf(s);
    }
  }
}

// K9: fused 5x5 stencil; CG=16 for LDS 25.6 KB -> 6 blocks/CU occupancy.
constexpr int TS = 16, CG = 16, TW = TS + 4;  // TW=20
__global__ void k_ffnconv2(const float* __restrict__ hcl, const float* __restrict__ w1,
                           const float* __restrict__ w3, const float* __restrict__ w5,
                           float* __restrict__ hc2) {
  int tile = blockIdx.x;
  int cg = blockIdx.y, b = blockIdx.z;
  int t = threadIdx.x;
  int ti0 = (tile >> 2) * TS, tj0 = (tile & 3) * TS;
  __shared__ float sm[TW * TW * CG];

  for (int e = t; e < TW * TW * CG; e += 256) {
    int ec = e & 15;
    int sp = e >> 4;
    int hi = sp / TW, hj = sp % TW;
    int gi = ti0 + hi - 2, gj = tj0 + hj - 2;
    float v = 0.f;
    if ((unsigned)gi < (unsigned)HH && (unsigned)gj < (unsigned)WW)
      v = hcl[((size_t)b * LL + gi * WW + gj) * HIDv + cg * CG + ec];
    sm[e] = v;
  }

  int c = t & 15;
  int q = t >> 4;                 // 0..15: column within tile
  int cglob = cg * CG + c;
  float wc[25];
#pragma unroll
  for (int di = 0; di < 5; ++di)
#pragma unroll
    for (int dj = 0; dj < 5; ++dj) {
      float w = w5[cglob * 25 + di * 5 + dj];
      if (di >= 1 && di <= 3 && dj >= 1 && dj <= 3)
        w += w3[cglob * 9 + (di - 1) * 3 + (dj - 1)];
      if (di == 2 && dj == 2) w += 1.f + w1[cglob];
      wc[di * 5 + dj] = w;
    }
  __syncthreads();

  float win[5][5];
#pragma unroll
  for (int di = 0; di < 4; ++di)
#pragma unroll
    for (int dj = 0; dj < 5; ++dj)
      win[di][dj] = sm[(di * TW + (q + dj)) * CG + c];
#pragma unroll
  for (int r = 0; r < 16; ++r) {
    int slot = (r + 4) % 5;
#pragma unroll
    for (int dj = 0; dj < 5; ++dj)
      win[slot][dj] = sm[(((r + 4) * TW) + (q + dj)) * CG + c];
    float s = 0.f;
#pragma unroll
    for (int di = 0; di < 5; ++di) {
      int wsl = (r + di) % 5;
#pragma unroll
      for (int dj = 0; dj < 5; ++dj)
        s += win[wsl][dj] * wc[di * 5 + dj];
    }
    hc2[((size_t)b * LL + (ti0 + r) * WW + (tj0 + q)) * HIDv + cglob] = s;
  }
}

// K10: LayerNorm(HID); LNROWS=8 for LDS 24.8 KB -> 6 blocks/CU occupancy.
constexpr int LNROWS = 8, LNPAD = 776;   // 768 + 8 pad (bank spread)
__global__ void k_ln2b(const float* __restrict__ hc2, const float* __restrict__ g,
                       const float* __restrict__ be,
                       short* __restrict__ hnBh, short* __restrict__ hnBl) {
  int r0 = blockIdx.x * LNROWS;
  int t = threadIdx.x;              // 256
  __shared__ float rows[LNROWS * LNPAD];
  __shared__ float m_[LNROWS], rs_[LNROWS];
  // load 8x768 once, coalesced float4
#pragma unroll
  for (int i = 0; i < 6; ++i) {
    int idx4 = t + i * 256;                 // 0..1535
    int row = idx4 / 192, c4 = idx4 % 192;
    float4 v = *(const float4*)(hc2 + (size_t)(r0 + row) * HIDv + c4 * 4);
    *(float4*)&rows[row * LNPAD + c4 * 4] = v;
  }
  __syncthreads();
  {
    int r = t >> 5, q = t & 31;
    float s = 0.f, qq = 0.f;
#pragma unroll
    for (int j = 0; j < 24; ++j) {
      float v = rows[r * LNPAD + q + j * 32];
      s += v; qq += v * v;
    }
    s += __shfl_down(s, 16, 32); qq += __shfl_down(qq, 16, 32);
    s += __shfl_down(s, 8, 32);  qq += __shfl_down(qq, 8, 32);
    s += __shfl_down(s, 4, 32);  qq += __shfl_down(qq, 4, 32);
    s += __shfl_down(s, 2, 32);  qq += __shfl_down(qq, 2, 32);
    s += __shfl_down(s, 1, 32);  qq += __shfl_down(qq, 1, 32);
    if (q == 0) {
      float m = s / HIDv;
      m_[r] = m;
      rs_[r] = rsqrtf(qq / HIDv - m * m + 1e-5f);
    }
  }
  __syncthreads();
#pragma unroll
  for (int i = 0; i < 6; ++i) {
    int idx4 = t + i * 256;
    int row = idx4 / 192, c4 = idx4 % 192;
    float4 v = *(const float4*)&rows[row * LNPAD + c4 * 4];
    float4 gv = *(const float4*)(g + c4 * 4);
    float4 bv = *(const float4*)(be + c4 * 4);
    float m = m_[row], rs = rs_[row];
    short4v hh, ll;
#pragma unroll
    for (int j = 0; j < 4; ++j) {
      float val = ((&v.x)[j] - m) * rs * (&gv.x)[j] + (&bv.x)[j];
      __hip_bfloat16 h = __float2bfloat16(val);
      hh[j] = *(short*)&h;
      ll[j] = bfbits(val - (float)h);
    }
    size_t o = (size_t)(r0 + row) * HIDv + c4 * 4;
    *(short4v*)(hnBh + o) = hh;
    *(short4v*)(hnBl + o) = ll;
  }
}

// K11 (MFMA, split-K x2): ks0 = opw GEMM + fow kt[0,12); ks1 = fow kt[12,24)+bias.
// part0 = accO + sk*accF0 ; part1 = sk*(accF1 + fob). dout = part0 + part1 (merge).
__global__ void k_finalmf(const short* __restrict__ hnBh, const short* __restrict__ hnBl,
                          const short* __restrict__ fowP,
                          const short* __restrict__ ygtBh, const short* __restrict__ ygtBl,
                          const short* __restrict__ opwP,
                          const float* __restrict__ fob, const float* __restrict__ skip,
                          float* __restrict__ part) {
  int t = threadIdx.x;            // 256
  int wv = t >> 6, lane = t & 63;
  int ln16 = lane & 15, qd = lane >> 4;
  int m0 = blockIdx.x * 64 + wv * 16;
  int ks = blockIdx.y;            // 0 or 1
  floatx4 accF[6];
  floatx4 zero4 = {0.f, 0.f, 0.f, 0.f};
#pragma unroll
  for (int nt = 0; nt < 6; ++nt) accF[nt] = zero4;
  const short* arh = hnBh + (size_t)(m0 + ln16) * HIDv + qd * 8;
  const short* arl = hnBl + (size_t)(m0 + ln16) * HIDv + qd * 8;
  int kt0 = ks * 12;
#pragma unroll 2
  for (int kt = kt0; kt < kt0 + 12; ++kt) {
    short8 ah = *(const short8*)(arh + kt * 32);
    short8 al = *(const short8*)(arl + kt * 32);
    const short* bh = fowP + ((size_t)(kt * 6) * 64 + lane) * 8;
    const short* bl = fowP + ((size_t)(144 + kt * 6) * 64 + lane) * 8;
#pragma unroll
    for (int nt = 0; nt < 6; ++nt) {
      short8 bhv = *(const short8*)(bh + (size_t)nt * 512);
      short8 blv = *(const short8*)(bl + (size_t)nt * 512);
      accF[nt] = __builtin_amdgcn_mfma_f32_16x16x32_bf16(ah, bhv, accF[nt], 0, 0, 0);
      accF[nt] = __builtin_amdgcn_mfma_f32_16x16x32_bf16(al, bhv, accF[nt], 0, 0, 0);
      accF[nt] = __builtin_amdgcn_mfma_f32_16x16x32_bf16(ah, blv, accF[nt], 0, 0, 0);
    }
  }
  float sk = skip[0];
  if (ks == 0) {
    floatx4 accO[6];
#pragma unroll
    for (int nt = 0; nt < 6; ++nt) accO[nt] = zero4;
    const short* orh = ygtBh + (size_t)(m0 + ln16) * DIv + qd * 8;
    const short* orl = ygtBl + (size_t)(m0 + ln16) * DIv + qd * 8;
#pragma unroll 2
    for (int kt = 0; kt < 6; ++kt) {
      short8 ah = *(const short8*)(orh + kt * 32);
      short8 al = *(const short8*)(orl + kt * 32);
      const short* bh = opwP + ((size_t)(kt * 6) * 64 + lane) * 8;
      const short* bl = opwP + ((size_t)(36 + kt * 6) * 64 + lane) * 8;
#pragma unroll
      for (int nt = 0; nt < 6; ++nt) {
        short8 bhv = *(const short8*)(bh + (size_t)nt * 512);
        short8 blv = *(const short8*)(bl + (size_t)nt * 512);
        accO[nt] = __builtin_amdgcn_mfma_f32_16x16x32_bf16(ah, bhv, accO[nt], 0, 0, 0);
        accO[nt] = __builtin_amdgcn_mfma_f32_16x16x32_bf16(al, bhv, accO[nt], 0, 0, 0);
        accO[nt] = __builtin_amdgcn_mfma_f32_16x16x32_bf16(ah, blv, accO[nt], 0, 0, 0);
      }
    }
#pragma unroll
    for (int nt = 0; nt < 6; ++nt) {
      int col = nt * 16 + ln16;
#pragma unroll
      for (int r = 0; r < 4; ++r) {
        int row = m0 + qd * 4 + r;
        part[(size_t)row * DMv + col] = accO[nt][r] + sk * accF[nt][r];
      }
    }
  } else {
#pragma unroll
    for (int nt = 0; nt < 6; ++nt) {
      int col = nt * 16 + ln16;
      float bv = fob[col];
#pragma unroll
      for (int r = 0; r < 4; ++r) {
        int row = m0 + qd * 4 + r;
        part[(size_t)NR * DMv + (size_t)row * DMv + col] = sk * (accF[nt][r] + bv);
      }
    }
  }
}

// K12: dout = part0 + part1 (float4 elementwise).
__global__ void k_finmerge(const float* __restrict__ part, float* __restrict__ dout) {
  size_t i = (size_t)blockIdx.x * 256 + threadIdx.x;
  const float4* p4 = (const float4*)part;
  size_t npart = (size_t)NR * DMv / 4;
  float4 a = p4[i], b = p4[i + npart];
  float4 r;
  r.x = a.x + b.x; r.y = a.y + b.y; r.z = a.z + b.z; r.w = a.w + b.w;
  ((float4*)dout)[i] = r;
}

extern "C" void kernel_launch(void* const* d_in, const int* in_sizes, int n_in,
                              void* d_out, int out_size, void* d_ws, size_t ws_size,
                              hipStream_t stream) {
  const float* x        = (const float*)d_in[0];
  const float* in_w     = (const float*)d_in[1];
  const float* conv_w   = (const float*)d_in[2];
  const float* conv_b   = (const float*)d_in[3];
  const float* xpw      = (const float*)d_in[4];
  const float* dtw      = (const float*)d_in[5];
  const float* dtb      = (const float*)d_in[6];
  const float* alogs    = (const float*)d_in[7];
  const float* Ds       = (const float*)d_in[8];
  const float* ong      = (const float*)d_in[9];
  const float* onb      = (const float*)d_in[10];
  const float* opw      = (const float*)d_in[11];
  const float* fiw      = (const float*)d_in[12];
  const float* fib      = (const float*)d_in[13];
  const float* dw1      = (const float*)d_in[14];
  const float* dw3      = (const float*)d_in[15];
  const float* dw5      = (const float*)d_in[16];
  const float* flg      = (const float*)d_in[17];
  const float* flb      = (const float*)d_in[18];
  const float* fow      = (const float*)d_in[19];
  const float* fob      = (const float*)d_in[20];
  const float* skip     = (const float*)d_in[21];

  // Workspace layout (aliased)
  float* ws    = (float*)d_ws;
  float* xi    = ws;                 // -> ygtBl
  float* z     = xi + S_xi;          // -> part (split-K partials, dead after comlnt)
  float* xc    = z + S_xi;
  float* xdbl  = xc + S_xi;
  float* scr   = xdbl + S_xdbl;      // xBh/xBl scratch -> S/P -> hcl -> hnBh/hnBl
  float* ys    = scr + S_big;        // xcBh/xcBl -> ys -> hc2
  float* wtiny = ys + S_big;         // persistent small buffers
  short* inwP  = (short*)wtiny;                            // 2*72*512 = 73728 shorts
  __hip_bfloat16* ygtB = (__hip_bfloat16*)(wtiny + 36864); // NR*192 bf16
  short* fiwP  = (short*)(wtiny + 36864) + (size_t)NR * DIv; // 288*512
  short* opwP  = fiwP + 288 * 512;                         // 2*36*512
  short* fowP  = opwP + 2 * 36 * 512;                      // 2*144*512
  short* wcatP = fowP + 2 * 144 * 512;                     // 2*2*30*512

  // Merged weight prep + x bf16 convert + fragment packing (612 blocks)
  short* xBh = (short*)scr;
  short* xBl = xBh + (size_t)NR * 96;
  k_wprep<<<612, 256, 0, stream>>>(fiw, opw, fow, in_w, xpw, x,
                                   xBh, xBl, inwP, fiwP, opwP, fowP, wcatP);

  // in_proj via MFMA (3-term hi/lo)
  dim3 gipm(NR / 64, 6);
  k_inprojmf<<<gipm, 256, 0, stream>>>(xBh, xBl, inwP, xi, z);

  // Fused dwconv + bf16 hi/lo emit (xcBh/xcBl into ys region)
  short* xcBh = (short*)ys;
  short* xcBl = xcBh + (size_t)NR * DIv;
  dim3 gdw(16, DIv / 32, BB);
  k_dwconv3<<<gdw, 256, 0, stream>>>(xi, conv_w, conv_b, xc, xcBh, xcBl);

  // x_dbl via MFMA (transpose folded into A-row addressing)
  dim3 gxd(LL / 64, 8);
  k_xdblmf<<<gxd, 256, 0, stream>>>(xcBh, xcBl, wcatP, xdbl);

  // Chunked scan: S/P in scr (xBh/xBl dead after inprojmf)
  float* Sbuf = scr;
  float* Pbuf = scr + S_sp;
  dim3 gs13(NC * 3, KKv, BB);
  dim3 gs2(3, KKv, BB);
  k_scan1<<<gs13, 256, 0, stream>>>(xdbl, xc, alogs, dtw, dtb, Sbuf, Pbuf);
  k_scan2<<<gs2, 256, 0, stream>>>(Sbuf, Pbuf);
  k_scan3<<<gs13, 256, 0, stream>>>(xdbl, xc, alogs, dtw, dtb, Sbuf, ys);

  // Fused combine + LN + silu-gate; 8 rows/block; emits ygtB hi + lo
  __hip_bfloat16* ygtBl = (__hip_bfloat16*)xi;
  k_comlnt<<<NR / 8, 256, 0, stream>>>(ys, xc, Ds, z, ong, onb, ygtB, ygtBl);

  // ffn_in (bf16 MFMA); hcl into scr (S/P dead after scan3)
  float* hcl = scr;
  dim3 gmf(NR / 64, HIDv / 64);      // (256, 12)
  k_ffnmf<<<gmf, 256, 0, stream>>>(ygtB, fiwP, fib, hcl);

  float* hc2 = ys;
  dim3 gc(16, HIDv / CG, BB);        // (16, 48, 4)
  k_ffnconv2<<<gc, 256, 0, stream>>>(hcl, dw1, dw3, dw5, hc2);

  // LayerNorm -> bf16 hi/lo row-major (into scr, over dead hcl)
  short* hnBh = (short*)scr;
  short* hnBl = hnBh + (size_t)NR * HIDv;
  k_ln2b<<<NR / LNROWS, 256, 0, stream>>>(hc2, flg, flb, hnBh, hnBl);

  // Fused final: split-K x2 into partials (z region, dead after comlnt), then merge
  float* partbuf = z;                 // 2 * NR * 96 floats = S_xi exactly
  dim3 gfm(NR / 64, 2);
  k_finalmf<<<gfm, 256, 0, stream>>>(hnBh, hnBl, fowP,
                                     (const short*)ygtB, (const short*)ygtBl, opwP,
                                     fob, skip, partbuf);
  k_finmerge<<<(NR * DMv / 4) / 256, 256, 0, stream>>>(partbuf, (float*)d_out);
}

// Round 11
// 383.965 us; speedup vs baseline: 1.5609x; 1.5609x over previous
//
#include <hip/hip_runtime.h>
#include <hip/hip_bf16.h>

constexpr int BB = 4, HH = 64, WW = 64, DMv = 96;
constexpr int DSn = 16, DIv = 192, DTRv = 6, KKv = 4, HIDv = 768;
constexpr int LL = 4096;
constexpr int NC = 64, CHK = LL / NC;       // 64 chunks of 64
constexpr int NR = BB * LL;                 // 16384 rows
constexpr int XDS = 40;                     // padded xdbl row stride (dt 0-5, B 8-23, C 24-39)

constexpr size_t S_xi   = (size_t)BB * LL * DIv;          // 3,145,728
constexpr size_t S_xdbl = (size_t)BB * KKv * LL * XDS;    // 2,621,440
constexpr size_t S_big  = (size_t)BB * KKv * LL * DIv;    // 12,582,912
constexpr size_t S_sp   = (size_t)BB * KKv * NC * DIv * DSn;  // 3,145,728 at NC=64

typedef __attribute__((ext_vector_type(8))) short short8;   // 8 bf16 (4 VGPRs)
typedef __attribute__((ext_vector_type(4))) short short4v;  // 4 bf16
typedef __attribute__((ext_vector_type(4))) float floatx4;  // MFMA accumulator

__device__ __forceinline__ float sigf(float x) { return 1.f / (1.f + __expf(-x)); }
__device__ __forceinline__ float softp(float x) {
  return (x > 20.f) ? x : __logf(1.f + __expf(x));
}
__device__ __forceinline__ short bfbits(float v) {
  __hip_bfloat16 h = __float2bfloat16(v);
  return *(short*)&h;
}

__device__ __forceinline__ int lmap(int k, int l) {
  int lr = (k & 2) ? (LL - 1 - l) : l;
  return (k & 1) ? (((lr & 63) << 6) | (lr >> 6)) : lr;
}

// K0: merged weight prep + x bf16 hi/lo convert + fragment packing.
// 0..383 xBh/xBl | 384..419 inwP(hi/lo) | 420..491 fiwP | 492..509 opwP(hi/lo) |
// 510..581 fowP(hi/lo) | 582..611 wcatP(hi/lo).
__global__ void k_wprep(const float* __restrict__ fiw, const float* __restrict__ opw,
                        const float* __restrict__ fow, const float* __restrict__ in_w,
                        const float* __restrict__ xpw, const float* __restrict__ x,
                        short* __restrict__ xBh, short* __restrict__ xBl,
                        short* __restrict__ inwP, short* __restrict__ fiwP,
                        short* __restrict__ opwP, short* __restrict__ fowP,
                        short* __restrict__ wcatP) {
  int bx = blockIdx.x, t = threadIdx.x;
  if (bx < 384) {  // x -> bf16 hi/lo, row-major streaming (NR*96 = 1.57M elems)
    const float4* x4 = (const float4*)x;
#pragma unroll
    for (int i = 0; i < 4; ++i) {
      int idx4 = bx * 1024 + i * 256 + t;     // < 393216
      float4 v = x4[idx4];
      short4v hh, ll;
#pragma unroll
      for (int j = 0; j < 4; ++j) {
        float val = (&v.x)[j];
        __hip_bfloat16 h = __float2bfloat16(val);
        hh[j] = *(short*)&h;
        ll[j] = bfbits(val - (float)h);
      }
      *(short4v*)(xBh + (size_t)idx4 * 4) = hh;
      *(short4v*)(xBl + (size_t)idx4 * 4) = ll;
    }
    return;
  }
  int lane = t & 63, ln16 = lane & 15, qd = lane >> 4;
  if (bx < 420) {  // inwP hi/lo: in_w [384][96]; frag f = kt*24+ntg (kt<3)
    int u = (bx - 384) * 4 + (t >> 6);   // 0..143
    int f = u >> 1, part = u & 1;        // f 0..71
    int kt = f / 24, ntg = f % 24;
    int n = ntg * 16 + ln16;
#pragma unroll
    for (int j = 0; j < 8; ++j) {
      int k = kt * 32 + qd * 8 + j;
      float w = in_w[(size_t)n * 96 + k];
      __hip_bfloat16 h = __float2bfloat16(w);
      float v = part ? (w - (float)h) : w;
      inwP[((size_t)(part * 72 + f)) * 512 + lane * 8 + j] = bfbits(v);
    }
    return;
  }
  if (bx < 492) {  // fiwP (hi only): frag f = kt*48+ntg
    int f = (bx - 420) * 4 + (t >> 6);   // 0..287
    int kt = f / 48, ntg = f % 48;
    int n = ntg * 16 + ln16;
#pragma unroll
    for (int j = 0; j < 8; ++j) {
      int k = kt * 32 + qd * 8 + j;
      fiwP[(size_t)f * 512 + lane * 8 + j] = bfbits(fiw[(size_t)n * DIv + k]);
    }
    return;
  }
  if (bx < 510) {  // opwP hi/lo: opw [96][192]; frag f = kt*6+ntg (kt<6)
    int u = (bx - 492) * 4 + (t >> 6);   // 0..71
    int f = u >> 1, part = u & 1;
    int kt = f / 6, ntg = f % 6;
    int n = ntg * 16 + ln16;
#pragma unroll
    for (int j = 0; j < 8; ++j) {
      int k = kt * 32 + qd * 8 + j;
      float w = opw[(size_t)n * DIv + k];
      __hip_bfloat16 h = __float2bfloat16(w);
      float v = part ? (w - (float)h) : w;
      opwP[((size_t)(part * 36 + f)) * 512 + lane * 8 + j] = bfbits(v);
    }
    return;
  }
  if (bx < 582) {  // fowP hi/lo: fow [96][768]; frag f = kt*6+ntg (kt<24)
    int u = (bx - 510) * 4 + (t >> 6);  // 0..287
    int f = u >> 1, part = u & 1;
    int kt = f / 6, ntg = f % 6;
    int n = ntg * 16 + ln16;
#pragma unroll
    for (int j = 0; j < 8; ++j) {
      int k = kt * 32 + qd * 8 + j;
      float w = fow[(size_t)n * HIDv + k];
      __hip_bfloat16 h = __float2bfloat16(w);
      float v = part ? (w - (float)h) : w;
      fowP[((size_t)(part * 144 + f)) * 512 + lane * 8 + j] = bfbits(v);
    }
    return;
  }
  {  // wcatP hi/lo: x_proj weights as B-frags; u -> p/part/kt/g
    int u = (bx - 582) * 4 + (t >> 6);  // 0..119
    int p = u / 60, r = u % 60;
    int part = r / 30, r2 = r % 30;
    int kt = r2 / 5, g = r2 % 5;
    int n = g * 16 + ln16;              // output col 0..79 (76..79 pad)
#pragma unroll
    for (int j = 0; j < 8; ++j) {
      int kd = kt * 32 + qd * 8 + j;
      float w = 0.f;
      if (n < 76) {
        int ksel = ((n >= 38) ? 2 : 0) + p;
        int cc = (n >= 38) ? n - 38 : n;
        w = xpw[(size_t)(ksel * 38 + cc) * DIv + kd];
      }
      __hip_bfloat16 h = __float2bfloat16(w);
      float v = part ? (w - (float)h) : w;
      wcatP[((size_t)(((p * 2 + part) * 6 + kt) * 5 + g)) * 512 + lane * 8 + j] = bfbits(v);
    }
  }
}

// K1 (MFMA): xz = x @ in_proj_w.T via 3-term hi/lo bf16. Grid (NR/64, 6).
__global__ void k_inprojmf(const short* __restrict__ xBh, const short* __restrict__ xBl,
                           const short* __restrict__ inwP,
                           float* __restrict__ xi, float* __restrict__ z) {
  int t = threadIdx.x;            // 256
  int wv = t >> 6, lane = t & 63;
  int ln16 = lane & 15, qd = lane >> 4;
  int m0 = blockIdx.x * 64 + wv * 16;
  int ntg0 = blockIdx.y * 4;      // 4 of 24 col-groups
  floatx4 acc[4];
  floatx4 zero4 = {0.f, 0.f, 0.f, 0.f};
#pragma unroll
  for (int nt = 0; nt < 4; ++nt) acc[nt] = zero4;
  const short* arh = xBh + (size_t)(m0 + ln16) * 96 + qd * 8;
  const short* arl = xBl + (size_t)(m0 + ln16) * 96 + qd * 8;
#pragma unroll
  for (int kt = 0; kt < 3; ++kt) {
    short8 ah = *(const short8*)(arh + kt * 32);
    short8 al = *(const short8*)(arl + kt * 32);
    const short* bh = inwP + ((size_t)(kt * 24 + ntg0) * 64 + lane) * 8;
    const short* bl = inwP + ((size_t)(72 + kt * 24 + ntg0) * 64 + lane) * 8;
#pragma unroll
    for (int nt = 0; nt < 4; ++nt) {
      short8 Bh = *(const short8*)(bh + (size_t)nt * 512);
      short8 Bl = *(const short8*)(bl + (size_t)nt * 512);
      acc[nt] = __builtin_amdgcn_mfma_f32_16x16x32_bf16(ah, Bh, acc[nt], 0, 0, 0);
      acc[nt] = __builtin_amdgcn_mfma_f32_16x16x32_bf16(al, Bh, acc[nt], 0, 0, 0);
      acc[nt] = __builtin_amdgcn_mfma_f32_16x16x32_bf16(ah, Bl, acc[nt], 0, 0, 0);
    }
  }
#pragma unroll
  for (int nt = 0; nt < 4; ++nt) {
    int col = blockIdx.y * 64 + nt * 16 + ln16;   // 0..383; uniform xi/z per block
#pragma unroll
    for (int r = 0; r < 4; ++r) {
      int row = m0 + qd * 4 + r;
      float v = acc[nt][r];
      if (col < DIv) xi[(size_t)row * DIv + col] = v;
      else           z[(size_t)row * DIv + col - DIv] = v;
    }
  }
}

// K2: xc = silu(dwconv3x3(xi)+b); emits xc f32 + bf16 hi/lo row-major.
constexpr int TW2 = 18;
__global__ void k_dwconv3(const float* __restrict__ xi, const float* __restrict__ cw,
                          const float* __restrict__ cb, float* __restrict__ xc,
                          short* __restrict__ xcBh, short* __restrict__ xcBl) {
  int tile = blockIdx.x;
  int cg = blockIdx.y, b = blockIdx.z;
  int t = threadIdx.x;
  int ti0 = (tile >> 2) * 16, tj0 = (tile & 3) * 16;
  __shared__ float sm[TW2 * TW2 * 32];

  for (int e = t; e < TW2 * TW2 * 32; e += 256) {
    int ec = e & 31;
    int sp = e >> 5;
    int hi = sp / TW2, hj = sp % TW2;
    int gi = ti0 + hi - 1, gj = tj0 + hj - 1;
    float v = 0.f;
    if ((unsigned)gi < (unsigned)HH && (unsigned)gj < (unsigned)WW)
      v = xi[((size_t)b * LL + gi * WW + gj) * DIv + cg * 32 + ec];
    sm[e] = v;
  }

  int c = t & 31, s0 = t >> 5;
  int cglob = cg * 32 + c;
  float wc[9];
#pragma unroll
  for (int j = 0; j < 9; ++j) wc[j] = cw[cglob * 9 + j];
  float bv = cb[cglob];
  __syncthreads();

  float res[32];
  for (int i = 0; i < 32; ++i) {
    int p = s0 + (i << 3);
    int r = p >> 4, q = p & 15;
    float s = bv;
#pragma unroll
    for (int di = 0; di < 3; ++di)
#pragma unroll
      for (int dj = 0; dj < 3; ++dj)
        s += sm[((r + di) * TW2 + (q + dj)) * 32 + c] * wc[di * 3 + dj];
    res[i] = s * sigf(s);
  }
  __syncthreads();
  for (int i = 0; i < 32; ++i) {
    int p = s0 + (i << 3);
    sm[p * 35 + c] = res[i];
  }
  __syncthreads();
  for (int it = 0; it < 32; ++it) {
    int e = it * 256 + t;
    int p = e >> 5, ec = e & 31;
    int l = (ti0 + (p >> 4)) * WW + tj0 + (p & 15);
    float v = sm[p * 35 + ec];
    size_t idx = ((size_t)b * LL + l) * DIv + cg * 32 + ec;
    xc[idx] = v;
    __hip_bfloat16 hh = __float2bfloat16(v);
    xcBh[idx] = *(short*)&hh;
    xcBl[idx] = bfbits(v - (float)hh);
  }
}

// K3 (MFMA): x_dbl = xs @ x_proj_w via hi/lo bf16; transpose folded into A rows.
__global__ void k_xdblmf(const short* __restrict__ xcBh, const short* __restrict__ xcBl,
                         const short* __restrict__ wcatP, float* __restrict__ xdbl) {
  int t = threadIdx.x;            // 256
  int wv = t >> 6, lane = t & 63;
  int ln16 = lane & 15, qd = lane >> 4;
  int pb = blockIdx.y;
  int p = pb >> 2, b = pb & 3;
  int m0 = blockIdx.x * 64 + wv * 16;
  int r = m0 + ln16;
  int l = p ? (((r & 63) << 6) | (r >> 6)) : r;
  const short* ah = xcBh + ((size_t)(b * LL + l)) * DIv + qd * 8;
  const short* al = xcBl + ((size_t)(b * LL + l)) * DIv + qd * 8;
  floatx4 acc[5];
  floatx4 zero4 = {0.f, 0.f, 0.f, 0.f};
#pragma unroll
  for (int g = 0; g < 5; ++g) acc[g] = zero4;
#pragma unroll
  for (int kt = 0; kt < 6; ++kt) {
    short8 Ah = *(const short8*)(ah + kt * 32);
    short8 Al = *(const short8*)(al + kt * 32);
    const short* bh = wcatP + ((size_t)(((p * 2 + 0) * 6 + kt) * 5)) * 512 + lane * 8;
    const short* bl = wcatP + ((size_t)(((p * 2 + 1) * 6 + kt) * 5)) * 512 + lane * 8;
#pragma unroll
    for (int g = 0; g < 5; ++g) {
      short8 Bh = *(const short8*)(bh + (size_t)g * 512);
      short8 Bl = *(const short8*)(bl + (size_t)g * 512);
      acc[g] = __builtin_amdgcn_mfma_f32_16x16x32_bf16(Ah, Bh, acc[g], 0, 0, 0);
      acc[g] = __builtin_amdgcn_mfma_f32_16x16x32_bf16(Al, Bh, acc[g], 0, 0, 0);
      acc[g] = __builtin_amdgcn_mfma_f32_16x16x32_bf16(Ah, Bl, acc[g], 0, 0, 0);
    }
  }
#pragma unroll
  for (int g = 0; g < 5; ++g) {
    int col = g * 16 + ln16;
    if (col < 76) {
#pragma unroll
      for (int rr = 0; rr < 4; ++rr) {
        int rowr = m0 + qd * 4 + rr;
        int kk = (col >= 38) ? (2 + p) : p;
        int cc = (col >= 38) ? col - 38 : col;
        int lpos = (col >= 38) ? (LL - 1 - rowr) : rowr;
        int phys = cc + (cc >= 6 ? 2 : 0);
        size_t ro = (((size_t)(b * KKv + kk)) * LL + lpos) * XDS;
        xdbl[ro + phys] = acc[g][rr];
        if (col == 5) { xdbl[ro + 6] = 0.f; xdbl[ro + 7] = 0.f; }
      }
    }
  }
}

// K4a: chunked scan pass 1. TEXTUALLY FROZEN (R6-verified): 16-row tiles,
// 4x __expf, A[4], de from global dt cols. THREE separate restructures spilled
// to scratch (VGPR 64, ~10x mem traffic): R5 exp2, R7 power-ladder, R10 32-row
// tiles. Do NOT modify this kernel in any way.
__global__ void k_scan1(const float* __restrict__ xdbl, const float* __restrict__ xc,
                        const float* __restrict__ alogs, const float* __restrict__ dtw,
                        const float* __restrict__ dtb,
                        float* __restrict__ S, float* __restrict__ P) {
  int bx = blockIdx.x;
  int c = bx / 3, dblk = bx % 3;
  int k = blockIdx.y, b = blockIdx.z;
  int t = threadIdx.x, dl = t >> 2, nq = t & 3;
  int d = dblk * 64 + dl;
  __shared__ float de_s[16][64], xv_s[16][64], bc_s[16][16];
  float A[4];
#pragma unroll
  for (int j = 0; j < 4; ++j)
    A[j] = -__expf(alogs[(size_t)(k * DIv + d) * DSn + nq * 4 + j]);
  int derow = t >> 4, dec0 = (t & 15) * 4;
  float DTW[4][6], DTB[4];
#pragma unroll
  for (int jj = 0; jj < 4; ++jj) {
    int dd = k * DIv + dblk * 64 + dec0 + jj;
    DTB[jj] = dtb[dd];
#pragma unroll
    for (int r2 = 0; r2 < 6; ++r2) DTW[jj][r2] = dtw[(size_t)dd * 6 + r2];
  }
  size_t bkL = (size_t)(b * KKv + k) * LL;
  const float* xq = xdbl + bkL * XDS;
  const float* xcb = xc + (size_t)b * LL * DIv;
  float h[4] = {0.f, 0.f, 0.f, 0.f}, sA[4] = {0.f, 0.f, 0.f, 0.f};
  int l0 = c * CHK;
  for (int tile = 0; tile < CHK / 16; ++tile) {
    int lt = l0 + tile * 16;
    __syncthreads();
    {
      int r = t >> 4, q = t & 15;
      int lc = lmap(k, lt + r);
      *(float4*)&xv_s[r][q * 4] = *(const float4*)(xcb + (size_t)lc * DIv + dblk * 64 + q * 4);
      if (t < 64) {
        int r2 = t >> 2, q2 = t & 3;
        *(float4*)&bc_s[r2][q2 * 4] = *(const float4*)(xq + (size_t)(lt + r2) * XDS + 8 + q2 * 4);
      }
      // de from global dt cols (same cache lines as B stage)
      const float* dtp = xq + (size_t)(lt + derow) * XDS;
      float d0 = dtp[0], d1 = dtp[1], d2 = dtp[2], d3 = dtp[3], d4 = dtp[4], d5 = dtp[5];
#pragma unroll
      for (int jj = 0; jj < 4; ++jj) {
        float s = DTB[jj] + d0 * DTW[jj][0] + d1 * DTW[jj][1] + d2 * DTW[jj][2]
                          + d3 * DTW[jj][3] + d4 * DTW[jj][4] + d5 * DTW[jj][5];
        de_s[derow][dec0 + jj] = softp(s);
      }
    }
    __syncthreads();
#pragma unroll
    for (int i2 = 0; i2 < 16; ++i2) {
      float de = de_s[i2][dl];
      float xv = xv_s[i2][dl];
      float4 Bv = *(float4*)&bc_s[i2][nq * 4];
      float db = de * xv;
#pragma unroll
      for (int j = 0; j < 4; ++j) {
        float u = de * A[j];
        sA[j] += u;
        h[j] = h[j] * __expf(u) + db * (&Bv.x)[j];
      }
    }
  }
  size_t o = ((((size_t)(b * KKv + k) * NC + c) * 3 + dblk) * 1024) + (size_t)t * 4;
  float4 hs, ps;
#pragma unroll
  for (int j = 0; j < 4; ++j) { (&hs.x)[j] = h[j]; (&ps.x)[j] = __expf(sA[j]); }
  *(float4*)(S + o) = hs;
  *(float4*)(P + o) = ps;
}

// K4b: sequential chunk combine (float4 per thread). Rewrites S[c] <- Hin[c].
__global__ void k_scan2(float* __restrict__ S, const float* __restrict__ P) {
  int dblk = blockIdx.x, k = blockIdx.y, b = blockIdx.z;
  int t = threadIdx.x;
  size_t base = (((size_t)(b * KKv + k) * NC) * 3 + dblk) * 1024 + (size_t)t * 4;
  float4 h = make_float4(0.f, 0.f, 0.f, 0.f);
  for (int c = 0; c < NC; ++c) {
    size_t o = base + (size_t)c * 3 * 1024;
    float4 s = *(float4*)(S + o), p = *(float4*)(P + o);
    *(float4*)(S + o) = h;
    h.x = s.x + p.x * h.x; h.y = s.y + p.y * h.y;
    h.z = s.z + p.z * h.z; h.w = s.w + p.w * h.w;
  }
}

// K4c: chunked scan pass 3 — TEXTUALLY FROZEN (R6-verified form).
// See k_scan1 note: three restructures (R5/R7/R10) all spilled. Do NOT modify.
__global__ void k_scan3(const float* __restrict__ xdbl, const float* __restrict__ xc,
                        const float* __restrict__ alogs, const float* __restrict__ dtw,
                        const float* __restrict__ dtb,
                        const float* __restrict__ Hin, float* __restrict__ ys) {
  int bx = blockIdx.x;
  int c = bx / 3, dblk = bx % 3;
  int k = blockIdx.y, b = blockIdx.z;
  int t = threadIdx.x, dl = t >> 2, nq = t & 3;
  int d = dblk * 64 + dl;
  __shared__ float de_s[16][64], xv_s[16][64], bc_s[16][32];
  float A[4];
#pragma unroll
  for (int j = 0; j < 4; ++j)
    A[j] = -__expf(alogs[(size_t)(k * DIv + d) * DSn + nq * 4 + j]);
  int derow = t >> 4, dec0 = (t & 15) * 4;
  float DTW[4][6], DTB[4];
#pragma unroll
  for (int jj = 0; jj < 4; ++jj) {
    int dd = k * DIv + dblk * 64 + dec0 + jj;
    DTB[jj] = dtb[dd];
#pragma unroll
    for (int r2 = 0; r2 < 6; ++r2) DTW[jj][r2] = dtw[(size_t)dd * 6 + r2];
  }
  size_t bkL = (size_t)(b * KKv + k) * LL;
  const float* xq = xdbl + bkL * XDS;
  const float* xcb = xc + (size_t)b * LL * DIv;
  float* yp = ys + bkL * DIv + d;
  size_t o = ((((size_t)(b * KKv + k) * NC + c) * 3 + dblk) * 1024) + (size_t)t * 4;
  float4 h4 = *(const float4*)(Hin + o);
  float h[4] = {h4.x, h4.y, h4.z, h4.w};
  int l0 = c * CHK;
  for (int tile = 0; tile < CHK / 16; ++tile) {
    int lt = l0 + tile * 16;
    __syncthreads();
    {
      int r = t >> 4, q = t & 15;
      int lc = lmap(k, lt + r);
      *(float4*)&xv_s[r][q * 4] = *(const float4*)(xcb + (size_t)lc * DIv + dblk * 64 + q * 4);
      if (t < 128) {
        int r2 = t >> 3, q2 = t & 7;
        *(float4*)&bc_s[r2][q2 * 4] = *(const float4*)(xq + (size_t)(lt + r2) * XDS + 8 + q2 * 4);
      }
      const float* dtp = xq + (size_t)(lt + derow) * XDS;
      float d0 = dtp[0], d1 = dtp[1], d2 = dtp[2], d3 = dtp[3], d4 = dtp[4], d5 = dtp[5];
#pragma unroll
      for (int jj = 0; jj < 4; ++jj) {
        float s = DTB[jj] + d0 * DTW[jj][0] + d1 * DTW[jj][1] + d2 * DTW[jj][2]
                          + d3 * DTW[jj][3] + d4 * DTW[jj][4] + d5 * DTW[jj][5];
        de_s[derow][dec0 + jj] = softp(s);
      }
    }
    __syncthreads();
#pragma unroll
    for (int i2 = 0; i2 < 16; ++i2) {
      float de = de_s[i2][dl];
      float xv = xv_s[i2][dl];
      float4 Bv = *(float4*)&bc_s[i2][nq * 4];
      float4 Cv = *(float4*)&bc_s[i2][16 + nq * 4];
      float db = de * xv;
      float p = 0.f;
#pragma unroll
      for (int j = 0; j < 4; ++j) {
        h[j] = h[j] * __expf(de * A[j]) + db * (&Bv.x)[j];
        p += h[j] * (&Cv.x)[j];
      }
      p += __shfl_down(p, 2, 4);
      p += __shfl_down(p, 1, 4);
      if (nq == 0) yp[(size_t)(lt + i2) * DIv] = p;
    }
  }
}

// K5+K6 fused (8 rows/block for occupancy); emits bf16 hi + lo of gated act.
__global__ void k_comlnt(const float* __restrict__ ys, const float* __restrict__ xc,
                         const float* __restrict__ Ds, const float* __restrict__ z,
                         const float* __restrict__ g, const float* __restrict__ be,
                         __hip_bfloat16* __restrict__ ygtB,
                         __hip_bfloat16* __restrict__ ygtBl) {
  int bl0 = blockIdx.x * 8;
  int b = bl0 >> 12, l0 = bl0 & 4095;
  int t = threadIdx.x;              // 256
  __shared__ float vbuf[8 * 193];
  __shared__ float m_[8], rs_[8];
  {
    int li = t >> 5, lane32 = t & 31;
    size_t base = (size_t)b * KKv * LL * DIv;
    int l = l0 + li;
    int lT = ((l & 63) << 6) | (l >> 6);
    const float* r0 = ys + base + (size_t)l * DIv;
    const float* r2 = ys + base + ((size_t)2 * LL + (LL - 1 - l)) * DIv;
    const float* r1 = ys + base + ((size_t)1 * LL + lT) * DIv;
    const float* r3 = ys + base + ((size_t)3 * LL + (LL - 1 - lT)) * DIv;
    const float* xr = xc + ((size_t)b * LL + l) * DIv;
#pragma unroll
    for (int cc = 0; cc < 6; ++cc) {
      int d = lane32 + cc * 32;
      float sd = Ds[d] + Ds[DIv + d] + Ds[2 * DIv + d] + Ds[3 * DIv + d];
      vbuf[li * 193 + d] = r0[d] + r2[d] + r1[d] + r3[d] + sd * xr[d];
    }
  }
  __syncthreads();
  {
    int r = t >> 5, q = t & 31;
    float s = 0.f, qq = 0.f;
#pragma unroll
    for (int j = 0; j < 6; ++j) {
      float v = vbuf[r * 193 + q + j * 32];
      s += v; qq += v * v;
    }
    s += __shfl_down(s, 16, 32); qq += __shfl_down(qq, 16, 32);
    s += __shfl_down(s, 8, 32);  qq += __shfl_down(qq, 8, 32);
    s += __shfl_down(s, 4, 32);  qq += __shfl_down(qq, 4, 32);
    s += __shfl_down(s, 2, 32);  qq += __shfl_down(qq, 2, 32);
    s += __shfl_down(s, 1, 32);  qq += __shfl_down(qq, 1, 32);
    if (q == 0) {
      float m = s / DIv;
      m_[r] = m;
      rs_[r] = rsqrtf(qq / DIv - m * m + 1e-5f);
    }
  }
  __syncthreads();
  int tc = t & 31, tr = t >> 5;     // tr = row 0..7
#pragma unroll
  for (int ch = 0; ch < 6; ++ch) {
    int c0 = ch * 32;
    float gg = g[c0 + tc], bb = be[c0 + tc];
    float v = vbuf[tr * 193 + c0 + tc];
    float zz = z[(size_t)(bl0 + tr) * DIv + c0 + tc];
    float val = (v - m_[tr]) * rs_[tr] * gg + bb;
    float gated = val * zz * sigf(zz);
    __hip_bfloat16 h = __float2bfloat16(gated);
    ygtB[(size_t)(bl0 + tr) * DIv + c0 + tc] = h;
    ygtBl[(size_t)(bl0 + tr) * DIv + c0 + tc] = __float2bfloat16(gated - (float)h);
  }
}

// K8 (MFMA): hcl = silu(ygated @ ffn_in_w.T + b) in bf16 MFMA, fp32 accumulate.
__global__ void k_ffnmf(const __hip_bfloat16* __restrict__ ygtB,
                        const short* __restrict__ fiwP,
                        const float* __restrict__ bias, float* __restrict__ hcl) {
  int t = threadIdx.x;            // 256
  int wv = t >> 6, lane = t & 63;
  int ln16 = lane & 15, qd = lane >> 4;
  int m0 = blockIdx.x * 64 + wv * 16;
  int n0 = blockIdx.y * 64;
  int ntg0 = n0 >> 4;             // first 16-col group
  floatx4 acc[4];
  floatx4 zero4 = {0.f, 0.f, 0.f, 0.f};
#pragma unroll
  for (int nt = 0; nt < 4; ++nt) acc[nt] = zero4;
  const short* arow = (const short*)ygtB + (size_t)(m0 + ln16) * DIv + qd * 8;
#pragma unroll
  for (int kt = 0; kt < 6; ++kt) {
    short8 a = *(const short8*)(arow + kt * 32);
    const short* bb = fiwP + ((size_t)(kt * 48 + ntg0) * 64 + lane) * 8;
#pragma unroll
    for (int nt = 0; nt < 4; ++nt) {
      short8 bfr = *(const short8*)(bb + (size_t)nt * 512);
      acc[nt] = __builtin_amdgcn_mfma_f32_16x16x32_bf16(a, bfr, acc[nt], 0, 0, 0);
    }
  }
  // C/D layout: col = lane&15, row = (lane>>4)*4 + reg  [m89-verified]
#pragma unroll
  for (int nt = 0; nt < 4; ++nt) {
    int col = n0 + nt * 16 + ln16;
    float bv = bias[col];
#pragma unroll
    for (int r = 0; r < 4; ++r) {
      int row = m0 + qd * 4 + r;
      float s = acc[nt][r] + bv;
      hcl[(size_t)row * HIDv + col] = s * sigf(s);
    }
  }
}

// K9: fused 5x5 stencil; CG=16 for LDS 25.6 KB -> 6 blocks/CU occupancy.
constexpr int TS = 16, CG = 16, TW = TS + 4;  // TW=20
__global__ void k_ffnconv2(const float* __restrict__ hcl, const float* __restrict__ w1,
                           const float* __restrict__ w3, const float* __restrict__ w5,
                           float* __restrict__ hc2) {
  int tile = blockIdx.x;
  int cg = blockIdx.y, b = blockIdx.z;
  int t = threadIdx.x;
  int ti0 = (tile >> 2) * TS, tj0 = (tile & 3) * TS;
  __shared__ float sm[TW * TW * CG];

  for (int e = t; e < TW * TW * CG; e += 256) {
    int ec = e & 15;
    int sp = e >> 4;
    int hi = sp / TW, hj = sp % TW;
    int gi = ti0 + hi - 2, gj = tj0 + hj - 2;
    float v = 0.f;
    if ((unsigned)gi < (unsigned)HH && (unsigned)gj < (unsigned)WW)
      v = hcl[((size_t)b * LL + gi * WW + gj) * HIDv + cg * CG + ec];
    sm[e] = v;
  }

  int c = t & 15;
  int q = t >> 4;                 // 0..15: column within tile
  int cglob = cg * CG + c;
  float wc[25];
#pragma unroll
  for (int di = 0; di < 5; ++di)
#pragma unroll
    for (int dj = 0; dj < 5; ++dj) {
      float w = w5[cglob * 25 + di * 5 + dj];
      if (di >= 1 && di <= 3 && dj >= 1 && dj <= 3)
        w += w3[cglob * 9 + (di - 1) * 3 + (dj - 1)];
      if (di == 2 && dj == 2) w += 1.f + w1[cglob];
      wc[di * 5 + dj] = w;
    }
  __syncthreads();

  float win[5][5];
#pragma unroll
  for (int di = 0; di < 4; ++di)
#pragma unroll
    for (int dj = 0; dj < 5; ++dj)
      win[di][dj] = sm[(di * TW + (q + dj)) * CG + c];
#pragma unroll
  for (int r = 0; r < 16; ++r) {
    int slot = (r + 4) % 5;
#pragma unroll
    for (int dj = 0; dj < 5; ++dj)
      win[slot][dj] = sm[(((r + 4) * TW) + (q + dj)) * CG + c];
    float s = 0.f;
#pragma unroll
    for (int di = 0; di < 5; ++di) {
      int wsl = (r + di) % 5;
#pragma unroll
      for (int dj = 0; dj < 5; ++dj)
        s += win[wsl][dj] * wc[di * 5 + dj];
    }
    hc2[((size_t)b * LL + (ti0 + r) * WW + (tj0 + q)) * HIDv + cglob] = s;
  }
}

// K10: LayerNorm(HID); LNROWS=8 for LDS 24.8 KB -> 6 blocks/CU occupancy.
constexpr int LNROWS = 8, LNPAD = 776;   // 768 + 8 pad (bank spread)
__global__ void k_ln2b(const float* __restrict__ hc2, const float* __restrict__ g,
                       const float* __restrict__ be,
                       short* __restrict__ hnBh, short* __restrict__ hnBl) {
  int r0 = blockIdx.x * LNROWS;
  int t = threadIdx.x;              // 256
  __shared__ float rows[LNROWS * LNPAD];
  __shared__ float m_[LNROWS], rs_[LNROWS];
  // load 8x768 once, coalesced float4
#pragma unroll
  for (int i = 0; i < 6; ++i) {
    int idx4 = t + i * 256;                 // 0..1535
    int row = idx4 / 192, c4 = idx4 % 192;
    float4 v = *(const float4*)(hc2 + (size_t)(r0 + row) * HIDv + c4 * 4);
    *(float4*)&rows[row * LNPAD + c4 * 4] = v;
  }
  __syncthreads();
  {
    int r = t >> 5, q = t & 31;
    float s = 0.f, qq = 0.f;
#pragma unroll
    for (int j = 0; j < 24; ++j) {
      float v = rows[r * LNPAD + q + j * 32];
      s += v; qq += v * v;
    }
    s += __shfl_down(s, 16, 32); qq += __shfl_down(qq, 16, 32);
    s += __shfl_down(s, 8, 32);  qq += __shfl_down(qq, 8, 32);
    s += __shfl_down(s, 4, 32);  qq += __shfl_down(qq, 4, 32);
    s += __shfl_down(s, 2, 32);  qq += __shfl_down(qq, 2, 32);
    s += __shfl_down(s, 1, 32);  qq += __shfl_down(qq, 1, 32);
    if (q == 0) {
      float m = s / HIDv;
      m_[r] = m;
      rs_[r] = rsqrtf(qq / HIDv - m * m + 1e-5f);
    }
  }
  __syncthreads();
#pragma unroll
  for (int i = 0; i < 6; ++i) {
    int idx4 = t + i * 256;
    int row = idx4 / 192, c4 = idx4 % 192;
    float4 v = *(const float4*)&rows[row * LNPAD + c4 * 4];
    float4 gv = *(const float4*)(g + c4 * 4);
    float4 bv = *(const float4*)(be + c4 * 4);
    float m = m_[row], rs = rs_[row];
    short4v hh, ll;
#pragma unroll
    for (int j = 0; j < 4; ++j) {
      float val = ((&v.x)[j] - m) * rs * (&gv.x)[j] + (&bv.x)[j];
      __hip_bfloat16 h = __float2bfloat16(val);
      hh[j] = *(short*)&h;
      ll[j] = bfbits(val - (float)h);
    }
    size_t o = (size_t)(r0 + row) * HIDv + c4 * 4;
    *(short4v*)(hnBh + o) = hh;
    *(short4v*)(hnBl + o) = ll;
  }
}

// K11 (MFMA, split-K x2): ks0 = opw GEMM + fow kt[0,12); ks1 = fow kt[12,24)+bias.
// part0 = accO + sk*accF0 ; part1 = sk*(accF1 + fob). dout = part0 + part1 (merge).
__global__ void k_finalmf(const short* __restrict__ hnBh, const short* __restrict__ hnBl,
                          const short* __restrict__ fowP,
                          const short* __restrict__ ygtBh, const short* __restrict__ ygtBl,
                          const short* __restrict__ opwP,
                          const float* __restrict__ fob, const float* __restrict__ skip,
                          float* __restrict__ part) {
  int t = threadIdx.x;            // 256
  int wv = t >> 6, lane = t & 63;
  int ln16 = lane & 15, qd = lane >> 4;
  int m0 = blockIdx.x * 64 + wv * 16;
  int ks = blockIdx.y;            // 0 or 1
  floatx4 accF[6];
  floatx4 zero4 = {0.f, 0.f, 0.f, 0.f};
#pragma unroll
  for (int nt = 0; nt < 6; ++nt) accF[nt] = zero4;
  const short* arh = hnBh + (size_t)(m0 + ln16) * HIDv + qd * 8;
  const short* arl = hnBl + (size_t)(m0 + ln16) * HIDv + qd * 8;
  int kt0 = ks * 12;
#pragma unroll 2
  for (int kt = kt0; kt < kt0 + 12; ++kt) {
    short8 ah = *(const short8*)(arh + kt * 32);
    short8 al = *(const short8*)(arl + kt * 32);
    const short* bh = fowP + ((size_t)(kt * 6) * 64 + lane) * 8;
    const short* bl = fowP + ((size_t)(144 + kt * 6) * 64 + lane) * 8;
#pragma unroll
    for (int nt = 0; nt < 6; ++nt) {
      short8 bhv = *(const short8*)(bh + (size_t)nt * 512);
      short8 blv = *(const short8*)(bl + (size_t)nt * 512);
      accF[nt] = __builtin_amdgcn_mfma_f32_16x16x32_bf16(ah, bhv, accF[nt], 0, 0, 0);
      accF[nt] = __builtin_amdgcn_mfma_f32_16x16x32_bf16(al, bhv, accF[nt], 0, 0, 0);
      accF[nt] = __builtin_amdgcn_mfma_f32_16x16x32_bf16(ah, blv, accF[nt], 0, 0, 0);
    }
  }
  float sk = skip[0];
  if (ks == 0) {
    floatx4 accO[6];
#pragma unroll
    for (int nt = 0; nt < 6; ++nt) accO[nt] = zero4;
    const short* orh = ygtBh + (size_t)(m0 + ln16) * DIv + qd * 8;
    const short* orl = ygtBl + (size_t)(m0 + ln16) * DIv + qd * 8;
#pragma unroll 2
    for (int kt = 0; kt < 6; ++kt) {
      short8 ah = *(const short8*)(orh + kt * 32);
      short8 al = *(const short8*)(orl + kt * 32);
      const short* bh = opwP + ((size_t)(kt * 6) * 64 + lane) * 8;
      const short* bl = opwP + ((size_t)(36 + kt * 6) * 64 + lane) * 8;
#pragma unroll
      for (int nt = 0; nt < 6; ++nt) {
        short8 bhv = *(const short8*)(bh + (size_t)nt * 512);
        short8 blv = *(const short8*)(bl + (size_t)nt * 512);
        accO[nt] = __builtin_amdgcn_mfma_f32_16x16x32_bf16(ah, bhv, accO[nt], 0, 0, 0);
        accO[nt] = __builtin_amdgcn_mfma_f32_16x16x32_bf16(al, bhv, accO[nt], 0, 0, 0);
        accO[nt] = __builtin_amdgcn_mfma_f32_16x16x32_bf16(ah, blv, accO[nt], 0, 0, 0);
      }
    }
#pragma unroll
    for (int nt = 0; nt < 6; ++nt) {
      int col = nt * 16 + ln16;
#pragma unroll
      for (int r = 0; r < 4; ++r) {
        int row = m0 + qd * 4 + r;
        part[(size_t)row * DMv + col] = accO[nt][r] + sk * accF[nt][r];
      }
    }
  } else {
#pragma unroll
    for (int nt = 0; nt < 6; ++nt) {
      int col = nt * 16 + ln16;
      float bv = fob[col];
#pragma unroll
      for (int r = 0; r < 4; ++r) {
        int row = m0 + qd * 4 + r;
        part[(size_t)NR * DMv + (size_t)row * DMv + col] = sk * (accF[nt][r] + bv);
      }
    }
  }
}

// K12: dout = part0 + part1 (float4 elementwise).
__global__ void k_finmerge(const float* __restrict__ part, float* __restrict__ dout) {
  size_t i = (size_t)blockIdx.x * 256 + threadIdx.x;
  const float4* p4 = (const float4*)part;
  size_t npart = (size_t)NR * DMv / 4;
  float4 a = p4[i], b = p4[i + npart];
  float4 r;
  r.x = a.x + b.x; r.y = a.y + b.y; r.z = a.z + b.z; r.w = a.w + b.w;
  ((float4*)dout)[i] = r;
}

extern "C" void kernel_launch(void* const* d_in, const int* in_sizes, int n_in,
                              void* d_out, int out_size, void* d_ws, size_t ws_size,
                              hipStream_t stream) {
  const float* x        = (const float*)d_in[0];
  const float* in_w     = (const float*)d_in[1];
  const float* conv_w   = (const float*)d_in[2];
  const float* conv_b   = (const float*)d_in[3];
  const float* xpw      = (const float*)d_in[4];
  const float* dtw      = (const float*)d_in[5];
  const float* dtb      = (const float*)d_in[6];
  const float* alogs    = (const float*)d_in[7];
  const float* Ds       = (const float*)d_in[8];
  const float* ong      = (const float*)d_in[9];
  const float* onb      = (const float*)d_in[10];
  const float* opw      = (const float*)d_in[11];
  const float* fiw      = (const float*)d_in[12];
  const float* fib      = (const float*)d_in[13];
  const float* dw1      = (const float*)d_in[14];
  const float* dw3      = (const float*)d_in[15];
  const float* dw5      = (const float*)d_in[16];
  const float* flg      = (const float*)d_in[17];
  const float* flb      = (const float*)d_in[18];
  const float* fow      = (const float*)d_in[19];
  const float* fob      = (const float*)d_in[20];
  const float* skip     = (const float*)d_in[21];

  // Workspace layout (aliased)
  float* ws    = (float*)d_ws;
  float* xi    = ws;                 // -> ygtBl
  float* z     = xi + S_xi;          // -> part (split-K partials, dead after comlnt)
  float* xc    = z + S_xi;
  float* xdbl  = xc + S_xi;
  float* scr   = xdbl + S_xdbl;      // xBh/xBl scratch -> S/P -> hcl -> hnBh/hnBl
  float* ys    = scr + S_big;        // xcBh/xcBl -> ys -> hc2
  float* wtiny = ys + S_big;         // persistent small buffers
  short* inwP  = (short*)wtiny;                            // 2*72*512 = 73728 shorts
  __hip_bfloat16* ygtB = (__hip_bfloat16*)(wtiny + 36864); // NR*192 bf16
  short* fiwP  = (short*)(wtiny + 36864) + (size_t)NR * DIv; // 288*512
  short* opwP  = fiwP + 288 * 512;                         // 2*36*512
  short* fowP  = opwP + 2 * 36 * 512;                      // 2*144*512
  short* wcatP = fowP + 2 * 144 * 512;                     // 2*2*30*512

  // Merged weight prep + x bf16 convert + fragment packing (612 blocks)
  short* xBh = (short*)scr;
  short* xBl = xBh + (size_t)NR * 96;
  k_wprep<<<612, 256, 0, stream>>>(fiw, opw, fow, in_w, xpw, x,
                                   xBh, xBl, inwP, fiwP, opwP, fowP, wcatP);

  // in_proj via MFMA (3-term hi/lo)
  dim3 gipm(NR / 64, 6);
  k_inprojmf<<<gipm, 256, 0, stream>>>(xBh, xBl, inwP, xi, z);

  // Fused dwconv + bf16 hi/lo emit (xcBh/xcBl into ys region)
  short* xcBh = (short*)ys;
  short* xcBl = xcBh + (size_t)NR * DIv;
  dim3 gdw(16, DIv / 32, BB);
  k_dwconv3<<<gdw, 256, 0, stream>>>(xi, conv_w, conv_b, xc, xcBh, xcBl);

  // x_dbl via MFMA (transpose folded into A-row addressing)
  dim3 gxd(LL / 64, 8);
  k_xdblmf<<<gxd, 256, 0, stream>>>(xcBh, xcBl, wcatP, xdbl);

  // Chunked scan: S/P in scr (xBh/xBl dead after inprojmf)
  float* Sbuf = scr;
  float* Pbuf = scr + S_sp;
  dim3 gs13(NC * 3, KKv, BB);
  dim3 gs2(3, KKv, BB);
  k_scan1<<<gs13, 256, 0, stream>>>(xdbl, xc, alogs, dtw, dtb, Sbuf, Pbuf);
  k_scan2<<<gs2, 256, 0, stream>>>(Sbuf, Pbuf);
  k_scan3<<<gs13, 256, 0, stream>>>(xdbl, xc, alogs, dtw, dtb, Sbuf, ys);

  // Fused combine + LN + silu-gate; 8 rows/block; emits ygtB hi + lo
  __hip_bfloat16* ygtBl = (__hip_bfloat16*)xi;
  k_comlnt<<<NR / 8, 256, 0, stream>>>(ys, xc, Ds, z, ong, onb, ygtB, ygtBl);

  // ffn_in (bf16 MFMA); hcl into scr (S/P dead after scan3)
  float* hcl = scr;
  dim3 gmf(NR / 64, HIDv / 64);      // (256, 12)
  k_ffnmf<<<gmf, 256, 0, stream>>>(ygtB, fiwP, fib, hcl);

  float* hc2 = ys;
  dim3 gc(16, HIDv / CG, BB);        // (16, 48, 4)
  k_ffnconv2<<<gc, 256, 0, stream>>>(hcl, dw1, dw3, dw5, hc2);

  // LayerNorm -> bf16 hi/lo row-major (into scr, over dead hcl)
  short* hnBh = (short*)scr;
  short* hnBl = hnBh + (size_t)NR * HIDv;
  k_ln2b<<<NR / LNROWS, 256, 0, stream>>>(hc2, flg, flb, hnBh, hnBl);

  // Fused final: split-K x2 into partials (z region, dead after comlnt), then merge
  float* partbuf = z;                 // 2 * NR * 96 floats = S_xi exactly
  dim3 gfm(NR / 64, 2);
  k_finalmf<<<gfm, 256, 0, stream>>>(hnBh, hnBl, fowP,
                                     (const short*)ygtB, (const short*)ygtBl, opwP,
                                     fob, skip, partbuf);
  k_finmerge<<<(NR * DMv / 4) / 256, 256, 0, stream>>>(partbuf, (float*)d_out);
}